// Round 1
// baseline (55.655 us; speedup 1.0000x reference)
//
#include <hip/hip_runtime.h>
#include <math.h>

#define NQ 8
#define NSTATES 256
#define DEPTH 2

__global__ __launch_bounds__(256) void qenc_kernel(
    const float* __restrict__ pf,     // [B, 8]
    const float* __restrict__ theta,  // [DEPTH, 8]
    const float* __restrict__ scale,  // [8]
    float* __restrict__ out,          // [B, 256]
    int B)
{
    const int wid_in_block = threadIdx.x >> 6;
    const int lane = threadIdx.x & 63;
    const int b = blockIdx.x * 4 + wid_in_block;
    if (b >= B) return;

    // Lanes 0..7 compute half-angles for (layer 0, layer 1) at qubit=lane.
    float h0 = 0.f, h1 = 0.f;
    if (lane < NQ) {
        float base = tanhf(pf[(size_t)b * NQ + lane]) * 3.14159265358979323846f * scale[lane];
        h0 = 0.5f * (base + theta[lane]);
        h1 = 0.5f * (base + theta[NQ + lane]);
    }

    // State: idx = lane*4 + i, amplitude in r0..r3. |0...0> start.
    float r0 = (lane == 0) ? 1.f : 0.f;
    float r1 = 0.f, r2 = 0.f, r3 = 0.f;

    // CZ diagonal sign per owned state index: (-1)^popc(idx & (idx>>1) & 0x7f)
    float sgn0, sgn1, sgn2, sgn3;
    {
        int i0 = lane * 4 + 0, i1 = lane * 4 + 1, i2 = lane * 4 + 2, i3 = lane * 4 + 3;
        sgn0 = (__popc(i0 & (i0 >> 1) & 0x7F) & 1) ? -1.f : 1.f;
        sgn1 = (__popc(i1 & (i1 >> 1) & 0x7F) & 1) ? -1.f : 1.f;
        sgn2 = (__popc(i2 & (i2 >> 1) & 0x7F) & 1) ? -1.f : 1.f;
        sgn3 = (__popc(i3 & (i3 >> 1) & 0x7F) & 1) ? -1.f : 1.f;
    }

    #pragma unroll
    for (int layer = 0; layer < DEPTH; ++layer) {
        #pragma unroll
        for (int q = 0; q < NQ; ++q) {
            float h = __shfl(layer == 0 ? h0 : h1, q, 64);  // uniform per wave
            float c = __cosf(h);
            float s = __sinf(h);
            if (q == 0) {
                // stride 1: pairs (r0,r1), (r2,r3)
                float n0 = c * r0 - s * r1;
                float n1 = s * r0 + c * r1;
                float n2 = c * r2 - s * r3;
                float n3 = s * r2 + c * r3;
                r0 = n0; r1 = n1; r2 = n2; r3 = n3;
            } else if (q == 1) {
                // stride 2: pairs (r0,r2), (r1,r3)
                float n0 = c * r0 - s * r2;
                float n2 = s * r0 + c * r2;
                float n1 = c * r1 - s * r3;
                float n3 = s * r1 + c * r3;
                r0 = n0; r1 = n1; r2 = n2; r3 = n3;
            } else {
                // stride 4..128: cross-lane butterfly, partner = lane ^ (1<<(q-2))
                int mask = 1 << (q - 2);
                float t0 = __shfl_xor(r0, mask, 64);
                float t1 = __shfl_xor(r1, mask, 64);
                float t2 = __shfl_xor(r2, mask, 64);
                float t3 = __shfl_xor(r3, mask, 64);
                if ((lane >> (q - 2)) & 1) {
                    // this lane holds s1 (bit q == 1): new1 = s*s0 + c*s1
                    r0 = s * t0 + c * r0;
                    r1 = s * t1 + c * r1;
                    r2 = s * t2 + c * r2;
                    r3 = s * t3 + c * r3;
                } else {
                    // holds s0: new0 = c*s0 - s*s1
                    r0 = c * r0 - s * t0;
                    r1 = c * r1 - s * t1;
                    r2 = c * r2 - s * t2;
                    r3 = c * r3 - s * t3;
                }
            }
        }
        // CZ phase after each layer
        r0 *= sgn0; r1 *= sgn1; r2 *= sgn2; r3 *= sgn3;
    }

    // L2 norm across the wave's 256 states
    float ss = r0 * r0 + r1 * r1 + r2 * r2 + r3 * r3;
    #pragma unroll
    for (int off = 1; off < 64; off <<= 1)
        ss += __shfl_xor(ss, off, 64);
    float inv = 1.f / fmaxf(sqrtf(ss), 1e-12f);

    float4 v = make_float4(r0 * inv, r1 * inv, r2 * inv, r3 * inv);
    *reinterpret_cast<float4*>(out + (size_t)b * NSTATES + (size_t)lane * 4) = v;
}

extern "C" void kernel_launch(void* const* d_in, const int* in_sizes, int n_in,
                              void* d_out, int out_size, void* d_ws, size_t ws_size,
                              hipStream_t stream) {
    const float* pf    = (const float*)d_in[0];  // [B, 8]
    const float* theta = (const float*)d_in[1];  // [2, 8]
    const float* scale = (const float*)d_in[2];  // [8]
    float* out = (float*)d_out;

    int B = in_sizes[0] / NQ;          // 65536
    int wavesPerBlock = 4;             // 256 threads
    int grid = (B + wavesPerBlock - 1) / wavesPerBlock;
    qenc_kernel<<<grid, 256, 0, stream>>>(pf, theta, scale, out, B);
}

// Round 2
// 30.257 us; speedup vs baseline: 1.8394x; 1.8394x over previous
//
#include <hip/hip_runtime.h>
#include <math.h>

#define PI_F 3.14159265358979323846f

// Single-instruction lane swizzle (compile-time pattern).
template <int PAT>
__device__ __forceinline__ float swzf(float x) {
    return __int_as_float(__builtin_amdgcn_ds_swizzle(__float_as_int(x), PAT));
}
// Broadcast from lane ((lane & 0x18) | SRC) within each 8-lane group.
#define BCAST(x, src) swzf<(((src) << 5) | 0x18)>(x)
// Butterfly exchange with lane ^ M.
#define BFLY(x, m) swzf<(((m) << 10) | 0x1F)>(x)

// Parity table: bit i = parity of popc(i & (i>>1) & 0xF)  (CZ pairs fully inside low 5 idx bits)
#define SLO_MASK 0x4748B848u

__global__ __launch_bounds__(256) void qenc_kernel(
    const float* __restrict__ pf,     // [B, 8]
    const float* __restrict__ theta,  // [2, 8]
    const float* __restrict__ scale,  // [8]
    float* __restrict__ out,          // [B, 256]
    int B)
{
    const int lane = threadIdx.x & 63;
    const int wid  = threadIdx.x >> 6;
    const int sub  = lane & 7;   // idx bits 5..7
    const int g    = lane >> 3;  // group within wave (8 batch elements / wave)
    const int b    = (blockIdx.x * 4 + wid) * 8 + g;
    if (b >= B) return;

    // ---- angles: lane `sub` computes qubit `sub` for BOTH layers (1 tanh each) ----
    float x  = pf[(size_t)b * 8 + sub];
    float e  = __expf(2.f * x);
    float th = 1.f - 2.f / (e + 1.f);          // tanh(x)
    float bounded = th * PI_F * scale[sub];
    float h0 = 0.5f * (bounded + theta[sub]);
    float h1 = 0.5f * (bounded + theta[8 + sub]);
    float c0 = __cosf(h0), s0 = __sinf(h0);    // layer 0
    float cL = __cosf(h1), sL = __sinf(h1);    // layer 1

    // ---- layer 0 on |0..0> is a tensor product: amp(idx) = prod_q f_q(bit_q) ----
    // idx = sub*32 + i ; qubits 0..4 <-> bits of i (compile-time), 5..7 <-> bits of sub.
    float KC0 = BCAST(c0, 0), KS0 = BCAST(s0, 0);
    float KC1 = BCAST(c0, 1), KS1 = BCAST(s0, 1);
    float KC2 = BCAST(c0, 2), KS2 = BCAST(s0, 2);
    float KC3 = BCAST(c0, 3), KS3 = BCAST(s0, 3);
    float KC4 = BCAST(c0, 4), KS4 = BCAST(s0, 4);
    float KC5 = BCAST(c0, 5), KS5 = BCAST(s0, 5);
    float KC6 = BCAST(c0, 6), KS6 = BCAST(s0, 6);
    float KC7 = BCAST(c0, 7), KS7 = BCAST(s0, 7);

    float f5 = (sub & 1) ? KS5 : KC5;
    float f6 = (sub & 2) ? KS6 : KC6;
    float f7 = (sub & 4) ? KS7 : KC7;
    float Phi = f5 * f6 * f7;                  // per-lane high-bit factor

    const float uu[4] = { Phi * (KC0 * KC1), Phi * (KS0 * KC1),
                          Phi * (KC0 * KS1), Phi * (KS0 * KS1) };
    float t23_0 = KC2 * KC3, t23_1 = KS2 * KC3, t23_2 = KC2 * KS3, t23_3 = KS2 * KS3;
    const float ww[8] = { t23_0 * KC4, t23_1 * KC4, t23_2 * KC4, t23_3 * KC4,
                          t23_0 * KS4, t23_1 * KS4, t23_2 * KS4, t23_3 * KS4 };

    float v[32];
#pragma unroll
    for (int i = 0; i < 32; ++i) v[i] = uu[i & 3] * ww[i >> 2];

    // ---- CZ sign #1 ----
    // pairs (5,6),(6,7): per-lane A ; pair (4,5): flips when (i&16) && (sub&1) ;
    // pairs (0,1)..(3,4): compile-time SLO_MASK over i.
    float A  = (__popc(sub & (sub >> 1) & 3) & 1) ? -1.f : 1.f;
    float A4 = (sub & 1) ? -A : A;
#pragma unroll
    for (int i = 0; i < 32; ++i) {
        float f = (i & 16) ? A4 : A;
        float r = v[i] * f;
        if ((SLO_MASK >> i) & 1) r = -r;
        v[i] = r;
    }

    // ---- layer 1: 5 intra-lane gates (q=0..4), 3 cross-lane gates (q=5..7) ----
#define INTRA_GATE(SB, CG, SG)                                        \
    do {                                                              \
        _Pragma("unroll")                                             \
        for (int base = 0; base < 32; base += 2 * (SB)) {             \
            _Pragma("unroll")                                         \
            for (int off = 0; off < (SB); ++off) {                    \
                int i0 = base + off, i1 = i0 + (SB);                  \
                float a = v[i0], bb = v[i1];                          \
                v[i0] = fmaf((CG), a, -((SG) * bb));                  \
                v[i1] = fmaf((CG), bb, (SG) * a);                     \
            }                                                         \
        }                                                             \
    } while (0)

#define CROSS_GATE(M, CG, SG)                                         \
    do {                                                              \
        float se = (sub & (M)) ? (SG) : -(SG);                        \
        _Pragma("unroll")                                             \
        for (int i = 0; i < 32; ++i) {                                \
            float t = BFLY(v[i], M);                                  \
            v[i] = fmaf((CG), v[i], se * t);                          \
        }                                                             \
    } while (0)

    {
        float cg, sg;
        cg = BCAST(cL, 0); sg = BCAST(sL, 0); INTRA_GATE(1,  cg, sg);
        cg = BCAST(cL, 1); sg = BCAST(sL, 1); INTRA_GATE(2,  cg, sg);
        cg = BCAST(cL, 2); sg = BCAST(sL, 2); INTRA_GATE(4,  cg, sg);
        cg = BCAST(cL, 3); sg = BCAST(sL, 3); INTRA_GATE(8,  cg, sg);
        cg = BCAST(cL, 4); sg = BCAST(sL, 4); INTRA_GATE(16, cg, sg);
        cg = BCAST(cL, 5); sg = BCAST(sL, 5); CROSS_GATE(1,  cg, sg);
        cg = BCAST(cL, 6); sg = BCAST(sL, 6); CROSS_GATE(2,  cg, sg);
        cg = BCAST(cL, 7); sg = BCAST(sL, 7); CROSS_GATE(4,  cg, sg);
    }

    // ---- norm over the 8-lane group (CZ signs don't change it) ----
    float ss = 0.f;
#pragma unroll
    for (int i = 0; i < 32; ++i) ss = fmaf(v[i], v[i], ss);
    ss += BFLY(ss, 1);
    ss += BFLY(ss, 2);
    ss += BFLY(ss, 4);
    float inv = rsqrtf(ss);   // ss ~= 1.0 exactly in infinite precision

    // ---- CZ sign #2 fused with normalization, then coalesced float4 stores ----
    float fA = A * inv, fA4 = A4 * inv;
#pragma unroll
    for (int i = 0; i < 32; ++i) {
        float f = (i & 16) ? fA4 : fA;
        float r = v[i] * f;
        if ((SLO_MASK >> i) & 1) r = -r;
        v[i] = r;
    }
    float4* op = (float4*)(out + (size_t)b * 256 + (size_t)sub * 32);
#pragma unroll
    for (int k = 0; k < 8; ++k)
        op[k] = make_float4(v[4 * k], v[4 * k + 1], v[4 * k + 2], v[4 * k + 3]);
}

extern "C" void kernel_launch(void* const* d_in, const int* in_sizes, int n_in,
                              void* d_out, int out_size, void* d_ws, size_t ws_size,
                              hipStream_t stream) {
    const float* pf    = (const float*)d_in[0];  // [B, 8]
    const float* theta = (const float*)d_in[1];  // [2, 8]
    const float* scale = (const float*)d_in[2];  // [8]
    float* out = (float*)d_out;

    int B = in_sizes[0] / 8;              // 65536
    int batchesPerBlock = 4 * 8;          // 4 waves * 8 batch elems
    int grid = (B + batchesPerBlock - 1) / batchesPerBlock;
    qenc_kernel<<<grid, 256, 0, stream>>>(pf, theta, scale, out, B);
}

// Round 4
// 20.404 us; speedup vs baseline: 2.7277x; 1.4829x over previous
//
#include <hip/hip_runtime.h>
#include <math.h>

#define PI_F 3.14159265358979323846f

// ---- single-instruction cross-lane primitives ----
// ds_swizzle BitMode (offset[15]=0): and=offset[4:0], or=offset[9:5], xor=offset[14:10]
// src_lane = (((lane[4:0] & and) | or) ^ xor), lane bit 5 preserved.
template <int PAT>
__device__ __forceinline__ float swzf(float x) {
    return __int_as_float(__builtin_amdgcn_ds_swizzle(__float_as_int(x), PAT));
}
// Broadcast (c,s) of qubit q from the group-lane with sub==q.
// Group lane bits to preserve within half: {2,4} -> and = 0x14 (bit 5 auto-preserved).
// or places q's 3 bits at lane bits 0,1,3.
#define BCAST_PAT(q) (((((q) & 3) | (((q) & 4) << 1)) << 5) | 0x14)

// DPP permute (VALU pipe, not LDS pipe)
template <int CTRL>
__device__ __forceinline__ float dppf(float x) {
    int i = __float_as_int(x);
    return __int_as_float(__builtin_amdgcn_update_dpp(i, i, CTRL, 0xF, 0xF, false));
}
#define DPP_XOR1 0xB1   // quad_perm [1,0,3,2]
#define DPP_XOR2 0x4E   // quad_perm [2,3,0,1]
#define DPP_XOR8 0x128  // row_ror:8 == lane^8 within 16-lane row

// Parity table: bit i = parity of popc(i & (i>>1) & 0xF)  (CZ pairs among idx bits 0..4)
#define SLO_MASK 0x4748B848u

__global__ __launch_bounds__(256) void qenc_kernel(
    const float* __restrict__ pf,     // [B, 8]
    const float* __restrict__ theta,  // [2, 8]
    const float* __restrict__ scale,  // [8]
    float* __restrict__ out,          // [B, 256]
    int B)
{
    const int lane = threadIdx.x & 63;
    const int wid  = threadIdx.x >> 6;
    // qubit bits 5,6,7 live on lane bits 0,1,3  (all DPP-reachable xors: 1,2,8)
    const int sub  = (lane & 3) | ((lane >> 1) & 4);
    // batch-in-wave on lane bits 2,4,5
    const int g    = ((lane >> 2) & 1) | ((lane >> 3) & 6);
    const int bwave = (blockIdx.x * 4 + wid) * 8;
    const int b = bwave + g;
    if (b >= B) return;

    __shared__ __align__(16) float lds[4 * 2048];   // 8 KB per wave
    float* base = lds + wid * 2048;

    // ---- angles: this lane handles qubit `sub` of batch `b`, both layers ----
    float x  = pf[(size_t)b * 8 + sub];
    float e  = __expf(2.f * x);
    float th = 1.f - 2.f / (e + 1.f);          // tanh(x)
    float bounded = th * PI_F * scale[sub];
    float h0 = 0.5f * (bounded + theta[sub]);
    float h1 = 0.5f * (bounded + theta[8 + sub]);
    float c0 = __cosf(h0), s0 = __sinf(h0);    // layer 0
    float cL = __cosf(h1), sL = __sinf(h1);    // layer 1

    // ---- broadcast all 8 qubits' (c,s) within the group ----
    float KC0 = swzf<BCAST_PAT(0)>(c0), KS0 = swzf<BCAST_PAT(0)>(s0);
    float KC1 = swzf<BCAST_PAT(1)>(c0), KS1 = swzf<BCAST_PAT(1)>(s0);
    float KC2 = swzf<BCAST_PAT(2)>(c0), KS2 = swzf<BCAST_PAT(2)>(s0);
    float KC3 = swzf<BCAST_PAT(3)>(c0), KS3 = swzf<BCAST_PAT(3)>(s0);
    float KC4 = swzf<BCAST_PAT(4)>(c0), KS4 = swzf<BCAST_PAT(4)>(s0);
    float KC5 = swzf<BCAST_PAT(5)>(c0), KS5 = swzf<BCAST_PAT(5)>(s0);
    float KC6 = swzf<BCAST_PAT(6)>(c0), KS6 = swzf<BCAST_PAT(6)>(s0);
    float KC7 = swzf<BCAST_PAT(7)>(c0), KS7 = swzf<BCAST_PAT(7)>(s0);

    // ---- layer 0 on |0..0> is a tensor product ----
    // idx = sub*32 + i (qubit q <-> idx bit q); qubits 5..7 are sub bits 0..2.
    float f5 = (sub & 1) ? KS5 : KC5;
    float f6 = (sub & 2) ? KS6 : KC6;
    float f7 = (sub & 4) ? KS7 : KC7;
    float Phi = f5 * f6 * f7;

    const float uu[4] = { Phi * (KC0 * KC1), Phi * (KS0 * KC1),
                          Phi * (KC0 * KS1), Phi * (KS0 * KS1) };
    float t23_0 = KC2 * KC3, t23_1 = KS2 * KC3, t23_2 = KC2 * KS3, t23_3 = KS2 * KS3;
    const float ww[8] = { t23_0 * KC4, t23_1 * KC4, t23_2 * KC4, t23_3 * KC4,
                          t23_0 * KS4, t23_1 * KS4, t23_2 * KS4, t23_3 * KS4 };

    float v[32];
#pragma unroll
    for (int i = 0; i < 32; ++i) v[i] = uu[i & 3] * ww[i >> 2];

    // ---- CZ sign #1 ----
    float A  = (__popc(sub & (sub >> 1) & 3) & 1) ? -1.f : 1.f;  // pairs (5,6),(6,7)
    float A4 = (sub & 1) ? -A : A;                               // pair (4,5) when i&16
#pragma unroll
    for (int i = 0; i < 32; ++i) {
        float f = (i & 16) ? A4 : A;
        float r = v[i] * f;
        if ((SLO_MASK >> i) & 1) r = -r;
        v[i] = r;
    }

    // ---- layer 1: 5 intra-lane gates (q0..q4), 3 DPP cross gates (q5..q7) ----
#define INTRA_GATE(SB, CG, SG)                                        \
    do {                                                              \
        _Pragma("unroll")                                             \
        for (int bse = 0; bse < 32; bse += 2 * (SB)) {                \
            _Pragma("unroll")                                         \
            for (int off = 0; off < (SB); ++off) {                    \
                int i0 = bse + off, i1 = i0 + (SB);                   \
                float a = v[i0], bb = v[i1];                          \
                v[i0] = fmaf((CG), a, -((SG) * bb));                  \
                v[i1] = fmaf((CG), bb, (SG) * a);                     \
            }                                                         \
        }                                                             \
    } while (0)

#define CROSS_GATE_DPP(CTRL, BIT, CG, SG)                             \
    do {                                                              \
        float se = (sub & (BIT)) ? (SG) : -(SG);                      \
        _Pragma("unroll")                                             \
        for (int i = 0; i < 32; ++i) {                                \
            float t = dppf<CTRL>(v[i]);                               \
            v[i] = fmaf((CG), v[i], se * t);                          \
        }                                                             \
    } while (0)

    {
        float cg, sg;
        cg = swzf<BCAST_PAT(0)>(cL); sg = swzf<BCAST_PAT(0)>(sL); INTRA_GATE(1,  cg, sg);
        cg = swzf<BCAST_PAT(1)>(cL); sg = swzf<BCAST_PAT(1)>(sL); INTRA_GATE(2,  cg, sg);
        cg = swzf<BCAST_PAT(2)>(cL); sg = swzf<BCAST_PAT(2)>(sL); INTRA_GATE(4,  cg, sg);
        cg = swzf<BCAST_PAT(3)>(cL); sg = swzf<BCAST_PAT(3)>(sL); INTRA_GATE(8,  cg, sg);
        cg = swzf<BCAST_PAT(4)>(cL); sg = swzf<BCAST_PAT(4)>(sL); INTRA_GATE(16, cg, sg);
        cg = swzf<BCAST_PAT(5)>(cL); sg = swzf<BCAST_PAT(5)>(sL); CROSS_GATE_DPP(DPP_XOR1, 1, cg, sg);
        cg = swzf<BCAST_PAT(6)>(cL); sg = swzf<BCAST_PAT(6)>(sL); CROSS_GATE_DPP(DPP_XOR2, 2, cg, sg);
        cg = swzf<BCAST_PAT(7)>(cL); sg = swzf<BCAST_PAT(7)>(sL); CROSS_GATE_DPP(DPP_XOR8, 4, cg, sg);
    }

    // ---- norm over the 8-lane group (DPP reduce; CZ signs don't change it) ----
    float ss = 0.f;
#pragma unroll
    for (int i = 0; i < 32; ++i) ss = fmaf(v[i], v[i], ss);
    ss += dppf<DPP_XOR1>(ss);
    ss += dppf<DPP_XOR2>(ss);
    ss += dppf<DPP_XOR8>(ss);
    float inv = rsqrtf(ss);

    // ---- CZ sign #2 fused with normalization ----
    float fA = A * inv, fA4 = A4 * inv;
#pragma unroll
    for (int i = 0; i < 32; ++i) {
        float f = (i & 16) ? fA4 : fA;
        float r = v[i] * f;
        if ((SLO_MASK >> i) & 1) r = -r;
        v[i] = r;
    }

    // ---- LDS transpose (within-wave, chunk-XOR swizzled) -> coalesced stores ----
    // logical chunk (16B) within a batch block: c = sub*8 + k ; phys = c ^ (c>>3)
#pragma unroll
    for (int k = 0; k < 8; ++k) {
        int c  = sub * 8 + k;
        int cp = c ^ sub;               // c ^ (c>>3)
        *reinterpret_cast<float4*>(base + g * 256 + cp * 4) =
            make_float4(v[4 * k], v[4 * k + 1], v[4 * k + 2], v[4 * k + 3]);
    }
    // read back transposed: iteration j writes batch (bwave+j), 64 lanes contiguous 1KB
    const int cr = lane ^ (lane >> 3);
#pragma unroll
    for (int j = 0; j < 8; ++j) {
        float4 t = *reinterpret_cast<const float4*>(base + j * 256 + cr * 4);
        *reinterpret_cast<float4*>(out + (size_t)(bwave + j) * 256 + lane * 4) = t;
    }
}

extern "C" void kernel_launch(void* const* d_in, const int* in_sizes, int n_in,
                              void* d_out, int out_size, void* d_ws, size_t ws_size,
                              hipStream_t stream) {
    const float* pf    = (const float*)d_in[0];  // [B, 8]
    const float* theta = (const float*)d_in[1];  // [2, 8]
    const float* scale = (const float*)d_in[2];  // [8]
    float* out = (float*)d_out;

    int B = in_sizes[0] / 8;              // 65536
    int batchesPerBlock = 4 * 8;          // 4 waves * 8 batch elems
    int grid = (B + batchesPerBlock - 1) / batchesPerBlock;
    qenc_kernel<<<grid, 256, 0, stream>>>(pf, theta, scale, out, B);
}